// Round 3
// baseline (73.891 us; speedup 1.0000x reference)
//
#include <hip/hip_runtime.h>

#define NPTS  4096
#define BQ    16
#define NT    256
#define OPT   8                 // outer points per thread (register-blocked)
#define SEG   4                 // inner-dimension segments
#define SEGN  (NPTS / SEG)      // 1024 inner points per segment
#define OTILE (NT * OPT)        // 2048 outer points per block
#define ILV   4                 // inner-loop unroll (points per LDS fetch group)

// Pass 1: grid (NPTS/OTILE=2, SEG=4, 32=dir*16+b) = 256 blocks, 1/CU.
// Each block: 2048 outer points vs one 1024-point inner segment.
// One ds_read_b128 feeds 8 pair-evals (24 fma + 4 min3 per inner point).
__global__ __launch_bounds__(NT, 2)
void chamfer_part_kernel(const float* __restrict__ preds,
                         const float* __restrict__ gts,
                         float* __restrict__ partial)
{
    __shared__ float4 s_pts[SEGN];   // 16 KB

    const int tile = blockIdx.x;          // 0..1
    const int seg  = blockIdx.y;          // 0..3
    const int bd   = blockIdx.z;          // 0..31
    const int dir  = bd >> 4;
    const int b    = bd & 15;

    const float* outer = (dir == 0) ? preds : gts;
    const float* inner = (dir == 0) ? gts   : preds;
    const float* ob = outer + (size_t)b * NPTS * 3;
    const float* ib = inner + (size_t)b * NPTS * 3 + (size_t)seg * SEGN * 3;

    // stage this inner segment into LDS as (x,y,z,||x||^2)
    for (int idx = (int)threadIdx.x; idx < SEGN; idx += NT) {
        const float x0 = ib[idx * 3 + 0];
        const float x1 = ib[idx * 3 + 1];
        const float x2 = ib[idx * 3 + 2];
        s_pts[idx] = make_float4(x0, x1, x2, x0 * x0 + x1 * x1 + x2 * x2);
    }

    // this thread's 8 outer points (coalesced per-u)
    float c0[OPT], c1[OPT], c2[OPT], yy[OPT];
#pragma unroll
    for (int u = 0; u < OPT; ++u) {
        const int o = tile * OTILE + u * NT + (int)threadIdx.x;
        const float y0 = ob[o * 3 + 0];
        const float y1 = ob[o * 3 + 1];
        const float y2 = ob[o * 3 + 2];
        yy[u] = y0 * y0 + y1 * y1 + y2 * y2;
        c0[u] = -2.0f * y0; c1[u] = -2.0f * y1; c2[u] = -2.0f * y2;
    }
    __syncthreads();

    float m[OPT];
#pragma unroll
    for (int u = 0; u < OPT; ++u) m[u] = 3.0e38f;

#pragma unroll 1
    for (int i = 0; i < SEGN; i += ILV) {
        float4 p[ILV];
#pragma unroll
        for (int k = 0; k < ILV; ++k) p[k] = s_pts[i + k];  // wave-uniform -> broadcast
#pragma unroll
        for (int u = 0; u < OPT; ++u) {
            const float t0 = fmaf(c0[u], p[0].x, fmaf(c1[u], p[0].y, fmaf(c2[u], p[0].z, p[0].w)));
            const float t1 = fmaf(c0[u], p[1].x, fmaf(c1[u], p[1].y, fmaf(c2[u], p[1].z, p[1].w)));
            m[u] = fminf(fminf(m[u], t0), t1);   // -> v_min3_f32
            const float t2 = fmaf(c0[u], p[2].x, fmaf(c1[u], p[2].y, fmaf(c2[u], p[2].z, p[2].w)));
            const float t3 = fmaf(c0[u], p[3].x, fmaf(c1[u], p[3].y, fmaf(c2[u], p[3].z, p[3].w)));
            m[u] = fminf(fminf(m[u], t2), t3);   // -> v_min3_f32
        }
    }

#pragma unroll
    for (int u = 0; u < OPT; ++u) {
        const int o = tile * OTILE + u * NT + (int)threadIdx.x;
        partial[((size_t)bd * NPTS + o) * SEG + seg] = m[u] + yy[u];
    }
}

// Pass 2: 131072 slots; min over SEG=4 partials per slot, local sum, block reduce.
__global__ void chamfer_comb_kernel(const float* __restrict__ partial,
                                    float* __restrict__ blockpart)
{
    __shared__ float s_red[NT];
    float sum = 0.0f;
#pragma unroll
    for (int i = 0; i < 4; ++i) {
        const int slot = (int)blockIdx.x * 1024 + i * NT + (int)threadIdx.x;
        const float4 p = ((const float4*)partial)[slot];
        sum += fminf(fminf(p.x, p.y), fminf(p.z, p.w));
    }
    s_red[threadIdx.x] = sum;
    __syncthreads();
#pragma unroll
    for (int s = NT / 2; s > 0; s >>= 1) {
        if ((int)threadIdx.x < s) s_red[threadIdx.x] += s_red[threadIdx.x + s];
        __syncthreads();
    }
    if (threadIdx.x == 0) blockpart[blockIdx.x] = s_red[0];
}

// Pass 3: sum 128 block partials, scale by 1/(B*N).
__global__ void chamfer_final_kernel(const float* __restrict__ blockpart,
                                     float* __restrict__ out)
{
    __shared__ float s_red[128];
    s_red[threadIdx.x] = blockpart[threadIdx.x];
    __syncthreads();
#pragma unroll
    for (int s = 64; s > 0; s >>= 1) {
        if ((int)threadIdx.x < s) s_red[threadIdx.x] += s_red[threadIdx.x + s];
        __syncthreads();
    }
    if (threadIdx.x == 0) out[0] = s_red[0] * (1.0f / (float)(BQ * NPTS));
}

extern "C" void kernel_launch(void* const* d_in, const int* in_sizes, int n_in,
                              void* d_out, int out_size, void* d_ws, size_t ws_size,
                              hipStream_t stream)
{
    const float* preds = (const float*)d_in[0];
    const float* gts   = (const float*)d_in[1];
    float* out       = (float*)d_out;
    float* partial   = (float*)d_ws;                          // 2 MB
    float* blockpart = partial + (size_t)2 * BQ * NPTS * SEG; // +128 floats

    dim3 grid1(NPTS / OTILE, SEG, 2 * BQ);   // (2, 4, 32) = 256 blocks
    chamfer_part_kernel<<<grid1, NT, 0, stream>>>(preds, gts, partial);
    chamfer_comb_kernel<<<128, NT, 0, stream>>>(partial, blockpart);
    chamfer_final_kernel<<<1, 128, 0, stream>>>(blockpart, out);
}

// Round 4
// 51.321 us; speedup vs baseline: 1.4398x; 1.4398x over previous
//
#include <hip/hip_runtime.h>

#define NPTS  4096
#define BQ    16
#define NT    256
#define OPT   8                 // outer points per thread (register-blocked)
#define SEG   8                 // inner-dimension segments
#define SEGN  (NPTS / SEG)      // 512 inner points per segment
#define OTILE (NT * OPT)        // 2048 outer points per block
#define ILV   4                 // inner-loop unroll

// Pass 1: grid (NPTS/OTILE=2, SEG=8, 32=dir*16+b) = 512 blocks, 2/CU (8 waves/CU).
// Each block: 2048 outer points vs one 512-point inner segment.
// One ds_read_b128 feeds 8 pair-evals (12 fma + 2 min3 per inner point per u-group).
__global__ __launch_bounds__(NT, 2)
void chamfer_part_kernel(const float* __restrict__ preds,
                         const float* __restrict__ gts,
                         float* __restrict__ partial)
{
    __shared__ float4 s_pts[SEGN];   // 8 KB

    const int tile = blockIdx.x;          // 0..1
    const int seg  = blockIdx.y;          // 0..7
    const int bd   = blockIdx.z;          // 0..31
    const int dir  = bd >> 4;
    const int b    = bd & 15;

    const float* outer = (dir == 0) ? preds : gts;
    const float* inner = (dir == 0) ? gts   : preds;
    const float* ob = outer + (size_t)b * NPTS * 3;
    const float* ib = inner + (size_t)b * NPTS * 3 + (size_t)seg * SEGN * 3;

    // stage this inner segment into LDS as (x,y,z,||x||^2)
    for (int idx = (int)threadIdx.x; idx < SEGN; idx += NT) {
        const float x0 = ib[idx * 3 + 0];
        const float x1 = ib[idx * 3 + 1];
        const float x2 = ib[idx * 3 + 2];
        s_pts[idx] = make_float4(x0, x1, x2, x0 * x0 + x1 * x1 + x2 * x2);
    }

    // this thread's 8 outer points (coalesced per-u)
    float c0[OPT], c1[OPT], c2[OPT], yy[OPT];
#pragma unroll
    for (int u = 0; u < OPT; ++u) {
        const int o = tile * OTILE + u * NT + (int)threadIdx.x;
        const float y0 = ob[o * 3 + 0];
        const float y1 = ob[o * 3 + 1];
        const float y2 = ob[o * 3 + 2];
        yy[u] = y0 * y0 + y1 * y1 + y2 * y2;
        c0[u] = -2.0f * y0; c1[u] = -2.0f * y1; c2[u] = -2.0f * y2;
    }
    __syncthreads();

    float m[OPT];
#pragma unroll
    for (int u = 0; u < OPT; ++u) m[u] = 3.0e38f;

#pragma unroll 1
    for (int i = 0; i < SEGN; i += ILV) {
        float4 p[ILV];
#pragma unroll
        for (int k = 0; k < ILV; ++k) p[k] = s_pts[i + k];  // wave-uniform -> broadcast
#pragma unroll
        for (int u = 0; u < OPT; ++u) {
            const float t0 = fmaf(c0[u], p[0].x, fmaf(c1[u], p[0].y, fmaf(c2[u], p[0].z, p[0].w)));
            const float t1 = fmaf(c0[u], p[1].x, fmaf(c1[u], p[1].y, fmaf(c2[u], p[1].z, p[1].w)));
            m[u] = fminf(fminf(m[u], t0), t1);   // -> v_min3_f32
            const float t2 = fmaf(c0[u], p[2].x, fmaf(c1[u], p[2].y, fmaf(c2[u], p[2].z, p[2].w)));
            const float t3 = fmaf(c0[u], p[3].x, fmaf(c1[u], p[3].y, fmaf(c2[u], p[3].z, p[3].w)));
            m[u] = fminf(fminf(m[u], t2), t3);   // -> v_min3_f32
        }
    }

#pragma unroll
    for (int u = 0; u < OPT; ++u) {
        const int o = tile * OTILE + u * NT + (int)threadIdx.x;
        partial[((size_t)bd * NPTS + o) * SEG + seg] = m[u] + yy[u];
    }
}

// Pass 2: 131072 slots; min over SEG=8 partials per slot, local sum, block reduce.
// grid 128 x 256, 4 slots/thread.
__global__ void chamfer_comb_kernel(const float* __restrict__ partial,
                                    float* __restrict__ blockpart)
{
    __shared__ float s_red[NT];
    float sum = 0.0f;
#pragma unroll
    for (int i = 0; i < 4; ++i) {
        const int slot = (int)blockIdx.x * 1024 + i * NT + (int)threadIdx.x;
        const float4 pa = ((const float4*)partial)[slot * 2 + 0];
        const float4 pb = ((const float4*)partial)[slot * 2 + 1];
        const float mn = fminf(fminf(fminf(pa.x, pa.y), fminf(pa.z, pa.w)),
                               fminf(fminf(pb.x, pb.y), fminf(pb.z, pb.w)));
        sum += mn;
    }
    s_red[threadIdx.x] = sum;
    __syncthreads();
#pragma unroll
    for (int s = NT / 2; s > 0; s >>= 1) {
        if ((int)threadIdx.x < s) s_red[threadIdx.x] += s_red[threadIdx.x + s];
        __syncthreads();
    }
    if (threadIdx.x == 0) blockpart[blockIdx.x] = s_red[0];
}

// Pass 3: sum 128 block partials, scale by 1/(B*N).
__global__ void chamfer_final_kernel(const float* __restrict__ blockpart,
                                     float* __restrict__ out)
{
    __shared__ float s_red[128];
    s_red[threadIdx.x] = blockpart[threadIdx.x];
    __syncthreads();
#pragma unroll
    for (int s = 64; s > 0; s >>= 1) {
        if ((int)threadIdx.x < s) s_red[threadIdx.x] += s_red[threadIdx.x + s];
        __syncthreads();
    }
    if (threadIdx.x == 0) out[0] = s_red[0] * (1.0f / (float)(BQ * NPTS));
}

extern "C" void kernel_launch(void* const* d_in, const int* in_sizes, int n_in,
                              void* d_out, int out_size, void* d_ws, size_t ws_size,
                              hipStream_t stream)
{
    const float* preds = (const float*)d_in[0];
    const float* gts   = (const float*)d_in[1];
    float* out       = (float*)d_out;
    float* partial   = (float*)d_ws;                          // 2*16*4096*8 floats = 4 MB
    float* blockpart = partial + (size_t)2 * BQ * NPTS * SEG; // +128 floats

    dim3 grid1(NPTS / OTILE, SEG, 2 * BQ);   // (2, 8, 32) = 512 blocks
    chamfer_part_kernel<<<grid1, NT, 0, stream>>>(preds, gts, partial);
    chamfer_comb_kernel<<<128, NT, 0, stream>>>(partial, blockpart);
    chamfer_final_kernel<<<1, 128, 0, stream>>>(blockpart, out);
}